// Round 1
// baseline (401.259 us; speedup 1.0000x reference)
//
#include <hip/hip_runtime.h>

// Stochastic LIF neuron scan:
//   u = 0.5*u + x[t]; u -= noise[t];
//   p = clip((u - 1.0 + 0.4)/0.8, 0, 1); o = (unif[t] < p);
//   u *= (1 - o)
// Output o as float32 [B,T,N]. Fixed shapes B=32, T=16, N=65536.
// One thread owns 4 consecutive n for one b; loops t=0..15 in registers.
// Memory-bound: 512 MiB total HBM traffic -> ~85us floor at 6.3 TB/s.

namespace {

constexpr int B = 32;
constexpr int T = 16;
constexpr int N = 65536;
constexpr int N4 = N / 4;            // 16384 float4 per (b,t) row
constexpr int N4_SHIFT = 14;         // log2(N4)

constexpr float SIGMA = 0.4f;        // A
constexpr float TWO_SIGMA = 0.8f;    // 2*A (fp32 value of python 0.8)
constexpr float THRESHOLD = 1.0f;
constexpr float TAU_INV = 0.5f;

// One timestep for one scalar lane element. Must match reference fp32
// op order exactly: mul+add (0.5*u exact so fma-safe), sub, sub, add,
// IEEE divide (do NOT replace with *1.25f), clamp, compare, mul.
__device__ __forceinline__ float lif_step(float& u, float xi, float ni, float ri) {
    u = TAU_INV * u + xi;            // leaky integrate
    u = u - ni;                      // noise injection
    float v = u - THRESHOLD;
    float p = (v + SIGMA) / TWO_SIGMA;  // IEEE fp32 divide, matches ref
    p = fminf(fmaxf(p, 0.0f), 1.0f);
    float o = (ri < p) ? 1.0f : 0.0f;
    u = u * (1.0f - o);              // hard reset where spiked
    return o;
}

__global__ __launch_bounds__(256) void snn_scan_kernel(
    const float4* __restrict__ x,
    const float4* __restrict__ noise,
    const float4* __restrict__ unif,
    float4* __restrict__ out)
{
    const int tid = blockIdx.x * blockDim.x + threadIdx.x;   // [0, B*N4)
    const int b  = tid >> N4_SHIFT;
    const int nc = tid & (N4 - 1);

    int idx = b * T * N4 + nc;       // float4 index of (b, t=0, nc)
    float4 u = make_float4(0.0f, 0.0f, 0.0f, 0.0f);

    for (int t = 0; t < T; ++t, idx += N4) {
        const float4 xi = x[idx];
        const float4 ni = noise[idx];
        const float4 ri = unif[idx];
        float4 o;
        o.x = lif_step(u.x, xi.x, ni.x, ri.x);
        o.y = lif_step(u.y, xi.y, ni.y, ri.y);
        o.z = lif_step(u.z, xi.z, ni.z, ri.z);
        o.w = lif_step(u.w, xi.w, ni.w, ri.w);
        out[idx] = o;
    }
}

} // namespace

extern "C" void kernel_launch(void* const* d_in, const int* in_sizes, int n_in,
                              void* d_out, int out_size, void* d_ws, size_t ws_size,
                              hipStream_t stream) {
    const float4* x     = (const float4*)d_in[0];
    const float4* noise = (const float4*)d_in[1];
    const float4* unif  = (const float4*)d_in[2];
    float4* out         = (float4*)d_out;

    const int threads_total = B * N4;            // 524288
    const int block = 256;
    const int grid = threads_total / block;      // 2048 blocks, ~8/CU

    snn_scan_kernel<<<grid, block, 0, stream>>>(x, noise, unif, out);
}

// Round 2
// 394.220 us; speedup vs baseline: 1.0179x; 1.0179x over previous
//
#include <hip/hip_runtime.h>

// Stochastic LIF neuron scan, fp32, shapes B=32, T=16, N=65536.
//   u = 0.5*u + x[t]; u -= noise[t];
//   p = clip((u - 1.0 + 0.4)/0.8, 0, 1); o = (unif[t] < p); u *= (1-o)
// Memory-bound: 512 MiB total HBM traffic -> ~85us floor at 6.3 TB/s.
//
// R1 was 166us (3.2 TB/s): rolled loop, vmcnt(0) before compute each t,
// only 3 KB in flight per wave. R2: software pipeline (prefetch t+1 during
// compute of t) + 2 independent (b,nc) scans per thread -> 12 KB in
// flight per wave, no dead time between load batches.

namespace {

constexpr int B = 32;
constexpr int T = 16;
constexpr int N = 65536;
constexpr int N4 = N / 4;            // 16384 float4 per (b,t) row
constexpr int N4_SHIFT = 14;         // log2(N4)
constexpr int HALF = (B / 2) * T * N4;  // float4 offset between scan pair (b, b+16)

constexpr float SIGMA = 0.4f;        // A
constexpr float TWO_SIGMA = 0.8f;    // 2*A
constexpr float THRESHOLD = 1.0f;
constexpr float TAU_INV = 0.5f;

// One timestep, one scalar element. Must match reference fp32 op order:
// mul+add (0.5*u exact, fma-safe), sub, sub, add, IEEE divide (do NOT
// fold to *1.25f), clamp, compare, mul.
__device__ __forceinline__ float lif_step(float& u, float xi, float ni, float ri) {
    u = TAU_INV * u + xi;            // leaky integrate
    u = u - ni;                      // noise injection
    float v = u - THRESHOLD;
    float p = (v + SIGMA) / TWO_SIGMA;  // IEEE fp32 divide
    p = fminf(fmaxf(p, 0.0f), 1.0f);
    float o = (ri < p) ? 1.0f : 0.0f;
    u = u * (1.0f - o);              // hard reset where spiked
    return o;
}

__device__ __forceinline__ float4 lif_step4(float4& u, const float4& xi,
                                            const float4& ni, const float4& ri) {
    float4 o;
    o.x = lif_step(u.x, xi.x, ni.x, ri.x);
    o.y = lif_step(u.y, xi.y, ni.y, ri.y);
    o.z = lif_step(u.z, xi.z, ni.z, ri.z);
    o.w = lif_step(u.w, xi.w, ni.w, ri.w);
    return o;
}

__global__ __launch_bounds__(256) void snn_scan_kernel(
    const float4* __restrict__ x,
    const float4* __restrict__ noise,
    const float4* __restrict__ unif,
    float4* __restrict__ out)
{
    const int tid = blockIdx.x * blockDim.x + threadIdx.x;   // [0, B/2 * N4)
    const int b0 = tid >> N4_SHIFT;                          // 0..15
    const int nc = tid & (N4 - 1);

    int idx0 = b0 * T * N4 + nc;     // scan 0: batch b0
    int idx1 = idx0 + HALF;          // scan 1: batch b0 + 16

    float4 u0 = make_float4(0.f, 0.f, 0.f, 0.f);
    float4 u1 = make_float4(0.f, 0.f, 0.f, 0.f);

    // prologue: load t=0 for both scans
    float4 cx0 = x[idx0], cn0 = noise[idx0], cr0 = unif[idx0];
    float4 cx1 = x[idx1], cn1 = noise[idx1], cr1 = unif[idx1];

    for (int t = 0; t < T - 1; ++t) {
        const int nidx0 = idx0 + N4;
        const int nidx1 = idx1 + N4;
        // issue t+1 loads before computing t: keeps 6 loads (12 KB/wave)
        // in flight across the compute+store phase
        float4 nx0 = x[nidx0], nn0 = noise[nidx0], nr0 = unif[nidx0];
        float4 nx1 = x[nidx1], nn1 = noise[nidx1], nr1 = unif[nidx1];

        out[idx0] = lif_step4(u0, cx0, cn0, cr0);
        out[idx1] = lif_step4(u1, cx1, cn1, cr1);

        cx0 = nx0; cn0 = nn0; cr0 = nr0;
        cx1 = nx1; cn1 = nn1; cr1 = nr1;
        idx0 = nidx0; idx1 = nidx1;
    }

    // epilogue: last timestep
    out[idx0] = lif_step4(u0, cx0, cn0, cr0);
    out[idx1] = lif_step4(u1, cx1, cn1, cr1);
}

} // namespace

extern "C" void kernel_launch(void* const* d_in, const int* in_sizes, int n_in,
                              void* d_out, int out_size, void* d_ws, size_t ws_size,
                              hipStream_t stream) {
    const float4* x     = (const float4*)d_in[0];
    const float4* noise = (const float4*)d_in[1];
    const float4* unif  = (const float4*)d_in[2];
    float4* out         = (float4*)d_out;

    const int threads_total = (B / 2) * N4;      // 262144 (2 scans/thread)
    const int block = 256;
    const int grid = threads_total / block;      // 1024 blocks, 4/CU

    snn_scan_kernel<<<grid, block, 0, stream>>>(x, noise, unif, out);
}